// Round 1
// baseline (515.568 us; speedup 1.0000x reference)
//
#include <hip/hip_runtime.h>
#include <math.h>

namespace {
constexpr int B_ = 2, CIN = 8, H_ = 224, W_ = 224;
constexpr int K_ = 7;
constexpr int F_ = 64, E_ = 8;
constexpr int N1 = 43, N2 = 43, N_ = N1 * N2;   // 1849
constexpr int M_ = 49;                           // candidates per query
constexpr int D_ = 800;                          // patch dim (C*P*P)
constexpr int HW = H_ * W_;

// workspace layout (floats).
constexpr size_t FHW = (size_t)B_ * F_ * HW;     // 6,422,528
constexpr size_t OFF_H1E = 0;                    // channels-last [b][h][w][64]
constexpr size_t OFF_H1T = OFF_H1E + FHW;
constexpr size_t OFF_H2E = OFF_H1T + FHW;        // NCHW
constexpr size_t OFF_H2T = OFF_H2E + FHW;
constexpr size_t OFF_WK  = 0;                                  // B*N*343
constexpr size_t OFF_NB  = 1280000;                            // > Wk end
constexpr size_t OFF_XE  = OFF_H2T + FHW;
constexpr size_t OFF_LTM = OFF_XE + (size_t)B_ * E_ * HW;
constexpr size_t OFF_PE  = OFF_LTM + (size_t)B_ * HW;
constexpr size_t OFF_YP  = OFF_PE + (size_t)B_ * N_ * D_;
constexpr size_t OFF_LT  = OFF_YP + (size_t)B_ * N_ * D_;
constexpr size_t OFF_SQ  = OFF_LT + (size_t)B_ * N_;
// conv2 prepped weights overlap the xe region (consumed by conv2 before
// conv3 writes xe): 2 buffers x 294912 ushorts = 294,912 floats < 802,816.
constexpr int WPREP_N = 294912;  // 2br * 2kcb * 9idx * 4wv * 64lane * 8j

__device__ __forceinline__ int clampi(int v, int lo, int hi) {
  return min(max(v, lo), hi);
}

typedef __attribute__((ext_vector_type(8))) short short8;
typedef __attribute__((ext_vector_type(4))) float float4v;
} // namespace

// ---------------------------------------------------------------------------
// conv1 (8->64, relu), e+t merged (z: bit0=batch, bit1=branch).
// R8: COG=16, 16x32 tile, 2 rows/thread -> each thread owns a full 64B line
// of the channels-last output (co0..co0+15), stored as 4x float4. Removes the
// cross-block partial-line write amplification (92MB -> ~55MB) and the 4B
// store scatter. launch_bounds(256,4) -> 4 blocks/CU.
// ---------------------------------------------------------------------------
__global__ __launch_bounds__(256, 4) void conv1m_k(
    const float* __restrict__ x,
    const float* __restrict__ w_e, const float* __restrict__ b_e, float* __restrict__ o_e,
    const float* __restrict__ w_t, const float* __restrict__ b_t, float* __restrict__ o_t) {
  constexpr int CI = 8, COG = 16, CIB = 4;
  constexpr int TR = 18, TC = 34;            // padded tile 18 rows x 34 cols
  constexpr int NST = CIB * TR * TC;         // 2448
  constexpr int NLD = (NST + 255) / 256;     // 10

  const int cog = blockIdx.x;                // 0..3
  const int tile = blockIdx.y;               // 0..97 (14 x 7)
  const int b = blockIdx.z & 1, br = blockIdx.z >> 1;
  const float* wgt = br ? w_t : w_e;
  const float* bias = br ? b_t : b_e;
  float* out = br ? o_t : o_e;
  const int co0 = cog * COG;
  const int th0 = (tile / 7) * 16, tw0 = (tile % 7) * 32;
  const int tid = threadIdx.x;
  const int tx = tid & 31, ty = tid >> 5;    // ty 0..7, 2 rows each

  __shared__ float sW[COG * CI * 12];        // 6144 B
  __shared__ float sT[CIB][TR * TC];         // 9792 B

  for (int s = tid; s < COG * CI * 12; s += 256) {
    int c = s / (CI * 12);
    int rem = s - c * (CI * 12);
    int ci = rem / 12, r = rem - ci * 12;
    sW[s] = (r < 9) ? wgt[((size_t)(co0 + c) * CI + ci) * 9 + r] : 0.f;
  }

  int po[NLD];
  unsigned okm = 0;
#pragma unroll
  for (int j = 0; j < NLD; ++j) {
    int s = tid + 256 * j;
    int pl = s / (TR * TC), rem = s - pl * (TR * TC);
    int lr = rem / TC, lc = rem - lr * TC;
    int gh = th0 + lr - 1, gw = tw0 + lc - 1;
    bool ok = (s < NST) && gh >= 0 && gh < H_ && gw >= 0 && gw < W_;
    po[j] = ok ? (pl * HW + gh * W_ + gw) : 0;
    if (ok) okm |= (1u << j);
  }

  const float* inB = x + (size_t)b * CI * HW;
  float stg[NLD];
#pragma unroll
  for (int j = 0; j < NLD; ++j) {
    float v = inB[po[j]];
    stg[j] = ((okm >> j) & 1) ? v : 0.f;
  }

  float acc[COG][2];
#pragma unroll
  for (int c = 0; c < COG; ++c) {
    float bv = bias[co0 + c];
    acc[c][0] = bv;
    acc[c][1] = bv;
  }

  for (int cb = 0; cb < CI; cb += CIB) {
    __syncthreads();
#pragma unroll
    for (int j = 0; j < NLD; ++j) {
      int s = tid + 256 * j;
      if (s < NST) ((float*)sT)[s] = stg[j];
    }
    __syncthreads();
    if (cb + CIB < CI) {
      const float* inN = inB + (size_t)(cb + CIB) * HW;
#pragma unroll
      for (int j = 0; j < NLD; ++j) {
        float v = inN[po[j]];
        stg[j] = ((okm >> j) & 1) ? v : 0.f;
      }
    }
#pragma unroll
    for (int ci = 0; ci < CIB; ++ci) {
      float iv[4][3];
#pragma unroll
      for (int r = 0; r < 4; ++r)
#pragma unroll
        for (int s2 = 0; s2 < 3; ++s2)
          iv[r][s2] = sT[ci][(2 * ty + r) * TC + tx + s2];
#pragma unroll
      for (int c = 0; c < COG; ++c) {
        const float4* wp = (const float4*)&sW[(c * CI + cb + ci) * 12];
        float4 wa = wp[0], wb = wp[1], wc = wp[2];
#pragma unroll
        for (int dy = 0; dy < 2; ++dy) {
          acc[c][dy] += iv[dy + 0][0] * wa.x + iv[dy + 0][1] * wa.y +
                        iv[dy + 0][2] * wa.z + iv[dy + 1][0] * wa.w +
                        iv[dy + 1][1] * wb.x + iv[dy + 1][2] * wb.y +
                        iv[dy + 2][0] * wb.z + iv[dy + 2][1] * wb.w +
                        iv[dy + 2][2] * wc.x;
        }
      }
    }
  }

#pragma unroll
  for (int dy = 0; dy < 2; ++dy) {
    int h = th0 + 2 * ty + dy, w = tw0 + tx;
    float* op = &out[(((size_t)b * H_ + h) * W_ + w) * 64 + co0];
#pragma unroll
    for (int g = 0; g < 4; ++g) {
      float4v v;
#pragma unroll
      for (int r = 0; r < 4; ++r) v[r] = fmaxf(acc[4 * g + r][dy], 0.f);
      *(float4v*)(op + 4 * g) = v;
    }
  }
}

// ---------------------------------------------------------------------------
// Weight prep for MFMA conv2 (unchanged).
// ---------------------------------------------------------------------------
__global__ __launch_bounds__(256) void wprep_k(const float* __restrict__ w_e,
                                               const float* __restrict__ w_t,
                                               unsigned short* __restrict__ whi,
                                               unsigned short* __restrict__ wlo) {
  int t = blockIdx.x * 256 + threadIdx.x;
  if (t >= WPREP_N) return;
  int j = t & 7;
  int lane = (t >> 3) & 63;
  int wv = (t >> 9) & 3;
  int t2 = t >> 11;
  int idx = t2 % 9;
  int t3 = t2 / 9;
  int kcb = t3 & 1;
  int br = t3 >> 1;
  const float* wgt = br ? w_t : w_e;
  int co = wv * 16 + (lane & 15);
  int ci = kcb * 32 + 8 * (lane >> 4) + j;
  float v = wgt[((size_t)co * 64 + ci) * 9 + idx];
  unsigned u = __float_as_uint(v);
  unsigned short hi = (unsigned short)(u >> 16);
  float rem = v - __uint_as_float(u & 0xffff0000u);
  unsigned short lo = (unsigned short)(__float_as_uint(rem) >> 16);
  whi[t] = hi;
  wlo[t] = lo;
}

// ---------------------------------------------------------------------------
// conv2 (64->64, relu) via MFMA bf16 3-term hi/lo split (unchanged).
// ---------------------------------------------------------------------------
__global__ __launch_bounds__(256) void conv2_mfma_k(
    const float* __restrict__ in_e, const float* __restrict__ in_t,
    const unsigned short* __restrict__ whi, const unsigned short* __restrict__ wlo,
    const float* __restrict__ b_e, const float* __restrict__ b_t,
    float* __restrict__ out_e, float* __restrict__ out_t) {
  const int tile = blockIdx.x;
  const int b = blockIdx.z & 1;
  const int br = blockIdx.z >> 1;
  const float* in = br ? in_t : in_e;
  const float* bias = br ? b_t : b_e;
  float* out = br ? out_t : out_e;

  const int th0 = (tile / 14) * 16, tw0 = (tile % 14) * 16;
  const int tid = threadIdx.x;
  const int wv = tid >> 6, lane = tid & 63;
  const int q = lane >> 4, n = lane & 15;

  __shared__ unsigned short sT[18 * 18 * 72];
  unsigned* sT32 = (unsigned*)sT;

  float4v acc[16];
#pragma unroll
  for (int pr = 0; pr < 16; ++pr) acc[pr] = (float4v)0.f;

  const float* inB = in + (size_t)b * HW * 64;
  const short8* whi8 = (const short8*)whi;
  const short8* wlo8 = (const short8*)wlo;

  for (int kcb = 0; kcb < 2; ++kcb) {
    __syncthreads();
    for (int jj = 0; jj < 21; ++jj) {
      int s = tid + 256 * jj;
      if (s < 5184) {
        int sp = s >> 4, cp = s & 15;
        int lr = sp / 18, lc = sp - lr * 18;
        int gh = th0 + lr - 1, gw = tw0 + lc - 1;
        float vx = 0.f, vy = 0.f;
        if (gh >= 0 && gh < H_ && gw >= 0 && gw < W_) {
          const float2 vv =
              *(const float2*)&inB[((size_t)gh * W_ + gw) * 64 + kcb * 32 + 2 * cp];
          vx = vv.x; vy = vv.y;
        }
        unsigned u0 = __float_as_uint(vx), u1 = __float_as_uint(vy);
        float r0 = vx - __uint_as_float(u0 & 0xffff0000u);
        float r1 = vy - __uint_as_float(u1 & 0xffff0000u);
        unsigned l0 = __float_as_uint(r0) >> 16, l1 = __float_as_uint(r1) >> 16;
        sT32[sp * 36 + cp] = (u0 >> 16) | ((u1 >> 16) << 16);
        sT32[sp * 36 + 16 + cp] = l0 | (l1 << 16);
      }
    }
    __syncthreads();

    short8 Ah[9], Al[9];
    const int abase = (((br * 2 + kcb) * 9) * 4 + wv) * 64 + lane;
#pragma unroll
    for (int idx = 0; idx < 9; ++idx) {
      Ah[idx] = whi8[abase + idx * 256];
      Al[idx] = wlo8[abase + idx * 256];
    }

#pragma unroll
    for (int r = 0; r < 18; ++r) {
      short8 Bh[3], Bl[3];
#pragma unroll
      for (int kx = 0; kx < 3; ++kx) {
        const unsigned short* p = &sT[(r * 18 + n + kx) * 72 + 8 * q];
        Bh[kx] = *(const short8*)p;
        Bl[kx] = *(const short8*)(p + 32);
      }
#pragma unroll
      for (int ky = 0; ky < 3; ++ky) {
        const int pr = r - ky;
        if (pr >= 0 && pr < 16) {
#pragma unroll
          for (int kx = 0; kx < 3; ++kx) {
            const int idx = ky * 3 + kx;
            acc[pr] = __builtin_amdgcn_mfma_f32_16x16x32_bf16(Ah[idx], Bh[kx], acc[pr], 0, 0, 0);
            acc[pr] = __builtin_amdgcn_mfma_f32_16x16x32_bf16(Al[idx], Bh[kx], acc[pr], 0, 0, 0);
            acc[pr] = __builtin_amdgcn_mfma_f32_16x16x32_bf16(Ah[idx], Bl[kx], acc[pr], 0, 0, 0);
          }
        }
      }
    }
  }

  float4v bv = *(const float4v*)&bias[wv * 16 + 4 * q];
#pragma unroll
  for (int pr = 0; pr < 16; ++pr) {
#pragma unroll
    for (int r = 0; r < 4; ++r) {
      int co = wv * 16 + 4 * q + r;
      float v = fmaxf(acc[pr][r] + bv[r], 0.f);
      out[((size_t)b * 64 + co) * HW + (th0 + pr) * W_ + tw0 + n] = v;
    }
  }
}

// ---------------------------------------------------------------------------
// conv3 e+t merged (64->8 from h2e, 64->1 from h2t, no relu).
// R8: 8x32 tile, 1 pixel/thread, CIB=4, grid (196, B) = 392 blocks (was 98 --
// occupancy 4.4%, 62% of CUs idle). LDS 38.5KB -> 4 blocks/CU.
// Same per-output FMA order as before -> bitwise-identical results.
// ---------------------------------------------------------------------------
__global__ __launch_bounds__(256, 4) void conv3m_k(
    const float* __restrict__ h2e, const float* __restrict__ h2t,
    const float* __restrict__ w3e, const float* __restrict__ w3t,
    const float* __restrict__ b3e, const float* __restrict__ b3t,
    float* __restrict__ xe, float* __restrict__ ltm) {
  constexpr int CIB = 4;
  constexpr int TR = 10, TC = 34;             // padded tile 10 x 34
  constexpr int PLN = TR * TC;                // 340
  constexpr int NST = 2 * CIB * PLN;          // 2720 (both branches)
  constexpr int NLD = (NST + 255) / 256;      // 11

  const int tile = blockIdx.x;                // 0..195 (28 x 7)
  const int b = blockIdx.y;
  const int th0 = (tile / 7) * 8, tw0 = (tile % 7) * 32;
  const int tid = threadIdx.x;
  const int tx = tid & 31, ty = tid >> 5;     // one output pixel per thread

  __shared__ float sW[9 * 64 * 12];           // 27648 B
  __shared__ float sT[2][CIB][PLN];           // 10880 B

  for (int s = tid; s < 9 * 64 * 12; s += 256) {
    int c = s / (64 * 12);
    int rem = s - c * (64 * 12);
    int ci = rem / 12, r = rem - ci * 12;
    float v = 0.f;
    if (r < 9)
      v = (c < 8) ? w3e[((size_t)c * 64 + ci) * 9 + r]
                  : w3t[(size_t)ci * 9 + r];
    sW[s] = v;
  }

  int po[NLD];
  unsigned okm = 0;
#pragma unroll
  for (int j = 0; j < NLD; ++j) {
    int s = tid + 256 * j;
    int rem2 = s % (CIB * PLN);
    int pl = rem2 / PLN, rem = rem2 % PLN;
    int lr = rem / TC, lc = rem - lr * TC;
    int gh = th0 + lr - 1, gw = tw0 + lc - 1;
    bool ok = (s < NST) && gh >= 0 && gh < H_ && gw >= 0 && gw < W_;
    po[j] = ok ? (pl * HW + gh * W_ + gw) : 0;
    if (ok) okm |= (1u << j);
  }

  const float* heB = h2e + (size_t)b * 64 * HW;
  const float* htB = h2t + (size_t)b * 64 * HW;

  float stg[NLD];
#pragma unroll
  for (int j = 0; j < NLD; ++j) {
    int s = tid + 256 * j;
    const float* src = (s < CIB * PLN) ? heB : htB;
    float v = src[po[j]];
    stg[j] = ((okm >> j) & 1) ? v : 0.f;
  }

  float acc[9];
#pragma unroll
  for (int c = 0; c < 9; ++c) acc[c] = (c < 8) ? b3e[c] : b3t[0];

  for (int cb = 0; cb < 64; cb += CIB) {
    __syncthreads();
#pragma unroll
    for (int j = 0; j < NLD; ++j) {
      int s = tid + 256 * j;
      if (s < NST) ((float*)sT)[s] = stg[j];
    }
    __syncthreads();
    if (cb + CIB < 64) {
      const size_t off = (size_t)(cb + CIB) * HW;
#pragma unroll
      for (int j = 0; j < NLD; ++j) {
        int s = tid + 256 * j;
        const float* src = (s < CIB * PLN) ? (heB + off) : (htB + off);
        float v = src[po[j]];
        stg[j] = ((okm >> j) & 1) ? v : 0.f;
      }
    }
#pragma unroll
    for (int ci = 0; ci < CIB; ++ci) {
      float ive[3][3], ivt[3][3];
#pragma unroll
      for (int r = 0; r < 3; ++r)
#pragma unroll
        for (int s2 = 0; s2 < 3; ++s2) {
          ive[r][s2] = sT[0][ci][(ty + r) * TC + tx + s2];
          ivt[r][s2] = sT[1][ci][(ty + r) * TC + tx + s2];
        }
#pragma unroll
      for (int c = 0; c < 9; ++c) {
        const float4* wp = (const float4*)&sW[(c * 64 + cb + ci) * 12];
        float4 wa = wp[0], wb = wp[1], wc = wp[2];
        const float (*iv)[3] = (c < 8) ? ive : ivt;
        acc[c] += iv[0][0] * wa.x + iv[0][1] * wa.y + iv[0][2] * wa.z +
                  iv[1][0] * wa.w + iv[1][1] * wb.x + iv[1][2] * wb.y +
                  iv[2][0] * wb.z + iv[2][1] * wb.w + iv[2][2] * wc.x;
      }
    }
  }

  const int h = th0 + ty, w = tw0 + tx;
#pragma unroll
  for (int c = 0; c < 8; ++c)
    xe[((size_t)(b * 8 + c) * H_ + h) * W_ + w] = acc[c];
  ltm[(size_t)b * HW + h * W_ + w] = acc[8];
}

// ---------------------------------------------------------------------------
// prep: per (b,n) block (256 thr): write pe row (from xe), yp row (from x),
// reduce sq = ||pe||^2 and lt = mean of 10x10 ltm patch. (unchanged)
// ---------------------------------------------------------------------------
__global__ __launch_bounds__(256) void prep_k(const float* __restrict__ xe,
                                              const float* __restrict__ x,
                                              const float* __restrict__ ltm,
                                              float* __restrict__ pe,
                                              float* __restrict__ yp,
                                              float* __restrict__ lt,
                                              float* __restrict__ sq) {
  const int n = blockIdx.x, b = blockIdx.y;
  const int tid = threadIdx.x;
  const int wv = tid >> 6, lane = tid & 63;
  const int q1 = n / N2, q2 = n % N2;
  const int r0 = q1 * 5, c0 = q2 * 5;

  float s = 0.f;
  float* peR = pe + ((size_t)b * N_ + n) * D_;
  float* ypR = yp + ((size_t)b * N_ + n) * D_;
#pragma unroll
  for (int j = 0; j < 4; ++j) {
    int d = tid + 256 * j;
    if (d < D_) {
      int c = d / 100;
      int rr = (d / 10) % 10;
      int cc = d % 10;
      size_t si = ((size_t)(b * 8 + c) * H_ + r0 + rr) * W_ + c0 + cc;
      float ve = xe[si];
      float vx = x[si];
      peR[d] = ve;
      ypR[d] = vx;
      s += ve * ve;
    }
  }
  float t = 0.f;
  if (tid < 100) t = ltm[(size_t)b * HW + (r0 + tid / 10) * W_ + c0 + tid % 10];

#pragma unroll
  for (int off = 32; off > 0; off >>= 1) {
    s += __shfl_xor(s, off);
    t += __shfl_xor(t, off);
  }
  __shared__ float rs[4], rt[4];
  if (lane == 0) { rs[wv] = s; rt[wv] = t; }
  __syncthreads();
  if (tid == 0) {
    sq[b * N_ + n] = rs[0] + rs[1] + rs[2] + rs[3];
    lt[b * N_ + n] = (rt[0] + rt[1] + rt[2] + rt[3]) * 0.01f;
  }
}

// ---------------------------------------------------------------------------
// attn stage 1 (unchanged).
// ---------------------------------------------------------------------------
__global__ __launch_bounds__(256) void attn_w_k(const float* __restrict__ pe,
                                                const float* __restrict__ lt,
                                                const float* __restrict__ sq,
                                                float* __restrict__ wk) {
  const int wv = threadIdx.x >> 6, lane = threadIdx.x & 63;
  const int n = blockIdx.x * 4 + wv;
  if (n >= N_) return;
  const int b = blockIdx.y;
  const int q1 = n / N2, q2 = n % N2;

  const float* peB = pe + (size_t)b * N_ * D_;
  const float* qrow = peB + (size_t)n * D_;
  float q[13];
#pragma unroll
  for (int t = 0; t < 13; ++t) {
    int s = t * 64 + lane;
    q[t] = (s < D_) ? qrow[s] : 0.f;
  }

  const float sqn = sq[b * N_ + n];
  const float itemp = expf(-lt[b * N_ + n]);
  float gm = -INFINITY;

  for (int o1 = 0; o1 < 7; ++o1) {
    int c1 = clampi(q1 + o1 - 3, 0, N1 - 1);
    const float* rowb = peB + (size_t)(c1 * N2) * D_;
#pragma unroll
    for (int o2 = 0; o2 < 7; ++o2) {
      int c2 = clampi(q2 + o2 - 3, 0, N2 - 1);
      int cn = c1 * N2 + c2;
      const float* crow = rowb + (size_t)c2 * D_;
      float a = 0.f;
#pragma unroll
      for (int t = 0; t < 13; ++t) {
        float v;
        if (t < 12) v = crow[t * 64 + lane];
        else v = (lane < 32) ? crow[768 + lane] : 0.f;
        a += q[t] * v;
      }
#pragma unroll
      for (int off = 32; off > 0; off >>= 1) a += __shfl_xor(a, off);
      float Dv = -(sqn + sq[b * N_ + cn] - 2.f * a);
      float lg = (cn == n) ? -1e9f : Dv * itemp;
      const int m = o1 * 7 + o2;
      gm = (lane == m) ? lg : gm;
    }
  }

  float cur = (lane < M_) ? gm : -INFINITY;
  float* wrow = wk + (size_t)(b * N_ + n) * (M_ * K_);
#pragma unroll
  for (int k = 0; k < K_; ++k) {
    float mx = cur;
#pragma unroll
    for (int off = 32; off > 0; off >>= 1) mx = fmaxf(mx, __shfl_xor(mx, off));
    float e = (lane < M_) ? expf(cur - mx) : 0.f;
    float ssum = e;
#pragma unroll
    for (int off = 32; off > 0; off >>= 1) ssum += __shfl_xor(ssum, off);
    float w = e / ssum;
    if (lane < M_) wrow[lane * K_ + k] = w;
    cur += log1pf(-fminf(w, 1.f - 1e-6f));
  }
}

// ---------------------------------------------------------------------------
// attn stage 2 (unchanged).
// ---------------------------------------------------------------------------
__global__ __launch_bounds__(256) void attn_pv_k(const float* __restrict__ yp,
                                                 const float* __restrict__ wk,
                                                 float* __restrict__ nb) {
  const int wv = threadIdx.x >> 6, lane = threadIdx.x & 63;
  const int n = blockIdx.x;
  const int b = blockIdx.z;
  const int sl = blockIdx.y * 4 + wv;
  const int d = sl * 64 + lane;
  if (d >= D_) return;
  const int q1 = n / N2, q2 = n % N2;

  const float* ypB = yp + (size_t)b * N_ * D_;
  const float* wrow = wk + (size_t)(b * N_ + n) * (M_ * K_);

  float acc[K_];
#pragma unroll
  for (int k = 0; k < K_; ++k) acc[k] = 0.f;

#pragma unroll
  for (int o1 = 0; o1 < 7; ++o1) {
    int c1 = clampi(q1 + o1 - 3, 0, N1 - 1);
#pragma unroll
    for (int o2 = 0; o2 < 7; ++o2) {
      int c2 = clampi(q2 + o2 - 3, 0, N2 - 1);
      int cn = c1 * N2 + c2;
      float y = ypB[(size_t)cn * D_ + d];
      const int m = o1 * 7 + o2;
#pragma unroll
      for (int k = 0; k < K_; ++k) acc[k] += wrow[m * K_ + k] * y;
    }
  }
#pragma unroll
  for (int k = 0; k < K_; ++k)
    nb[(((size_t)k * B_ + b) * N_ + n) * D_ + d] = acc[k];
}

// ---------------------------------------------------------------------------
// Fused output: channels 0..7 copy x; channels 8..63 fold-gather from nb.
// ---------------------------------------------------------------------------
__global__ __launch_bounds__(256) void foldcopy_k(const float* __restrict__ x,
                                                  const float* __restrict__ nb,
                                                  float* __restrict__ out) {
  int i = blockIdx.x * 256 + threadIdx.x;
  constexpr int CT = CIN * (K_ + 1);  // 64
  constexpr int TOT = B_ * CT * HW;
  if (i >= TOT) return;
  int w = i % W_;
  int h = (i / W_) % H_;
  int c64 = (i / HW) % CT;
  int b = i / (HW * CT);
  if (c64 < CIN) {
    out[i] = x[((size_t)b * CIN + c64) * HW + h * W_ + w];
    return;
  }
  int k = (c64 - CIN) >> 3, c = (c64 - CIN) & 7;
  int q1lo = max(0, (h - 5) / 5), q1hi = min(N1 - 1, h / 5);
  int q2lo = max(0, (w - 5) / 5), q2hi = min(N2 - 1, w / 5);
  float val = 0.f;
  int cnt = 0;
  for (int q1 = q1lo; q1 <= q1hi; ++q1)
    for (int q2 = q2lo; q2 <= q2hi; ++q2) {
      int i0 = h - 5 * q1, j0 = w - 5 * q2;
      int nn = q1 * N2 + q2;
      val += nb[(((size_t)k * B_ + b) * N_ + nn) * D_ + c * 100 + i0 * 10 + j0];
      ++cnt;
    }
  out[i] = (cnt > 0) ? val / (float)cnt : 0.f;
}

extern "C" void kernel_launch(void* const* d_in, const int* in_sizes, int n_in,
                              void* d_out, int out_size, void* d_ws,
                              size_t ws_size, hipStream_t stream) {
  const float* x   = (const float*)d_in[0];
  const float* w1e = (const float*)d_in[1];
  const float* b1e = (const float*)d_in[2];
  const float* w2e = (const float*)d_in[3];
  const float* b2e = (const float*)d_in[4];
  const float* w3e = (const float*)d_in[5];
  const float* b3e = (const float*)d_in[6];
  const float* w1t = (const float*)d_in[7];
  const float* b1t = (const float*)d_in[8];
  const float* w2t = (const float*)d_in[9];
  const float* b2t = (const float*)d_in[10];
  const float* w3t = (const float*)d_in[11];
  const float* b3t = (const float*)d_in[12];

  float* ws  = (float*)d_ws;
  float* out = (float*)d_out;

  float* h1e = ws + OFF_H1E;   // channels-last
  float* h1t = ws + OFF_H1T;   // channels-last
  float* h2e = ws + OFF_H2E;   // NCHW
  float* h2t = ws + OFF_H2T;   // NCHW
  float* wkb = ws + OFF_WK;
  float* nb  = ws + OFF_NB;
  float* xe  = ws + OFF_XE;
  float* ltm = ws + OFF_LTM;
  float* pe  = ws + OFF_PE;
  float* yp  = ws + OFF_YP;
  float* lt  = ws + OFF_LT;
  float* sqv = ws + OFF_SQ;
  unsigned short* whi = (unsigned short*)(ws + OFF_XE);  // consumed before xe written
  unsigned short* wlo = whi + WPREP_N;

  // conv2 weight prep
  wprep_k<<<(WPREP_N + 255) / 256, 256, 0, stream>>>(w2e, w2t, whi, wlo);
  // conv1 (8 -> 64, relu), e+t in one dispatch, channels-last output
  conv1m_k<<<dim3(4, 98, 4), 256, 0, stream>>>(x, w1e, b1e, h1e, w1t, b1t, h1t);
  // conv2 (64 -> 64, relu) via MFMA, both branches + batches in one dispatch
  conv2_mfma_k<<<dim3(196, 1, 4), 256, 0, stream>>>(h1e, h1t, whi, wlo, b2e, b2t, h2e, h2t);
  // conv3 (64 -> 8 + 64 -> 1) merged, 392 blocks
  conv3m_k<<<dim3(196, B_), 256, 0, stream>>>(h2e, h2t, w3e, w3t, b3e, b3t, xe, ltm);
  // patches + norms + log-temp means fused
  prep_k<<<dim3(N_, B_), 256, 0, stream>>>(xe, x, ltm, pe, yp, lt, sqv);
  // attention stage 1: weights
  attn_w_k<<<dim3((N_ + 3) / 4, B_), 256, 0, stream>>>(pe, lt, sqv, wkb);
  // attention stage 2: weighted neighbor sums
  attn_pv_k<<<dim3(N_, 4, B_), 256, 0, stream>>>(yp, wkb, nb);
  // fused fold + x passthrough
  constexpr int FT = B_ * CIN * (K_ + 1) * HW;
  foldcopy_k<<<(FT + 255) / 256, 256, 0, stream>>>(x, nb, out);
}

// Round 2
// 476.281 us; speedup vs baseline: 1.0825x; 1.0825x over previous
//
#include <hip/hip_runtime.h>
#include <math.h>

namespace {
constexpr int B_ = 2, CIN = 8, H_ = 224, W_ = 224;
constexpr int K_ = 7;
constexpr int F_ = 64, E_ = 8;
constexpr int N1 = 43, N2 = 43, N_ = N1 * N2;   // 1849
constexpr int M_ = 49;                           // candidates per query
constexpr int D_ = 800;                          // patch dim (C*P*P)
constexpr int HW = H_ * W_;

// workspace layout (floats).
constexpr size_t FHW = (size_t)B_ * F_ * HW;     // 6,422,528
constexpr size_t OFF_H1E = 0;                    // channels-last [b][h][w][64]
constexpr size_t OFF_H1T = OFF_H1E + FHW;
constexpr size_t OFF_H2E = OFF_H1T + FHW;        // NCHW
constexpr size_t OFF_H2T = OFF_H2E + FHW;
constexpr size_t OFF_WK  = 0;                                  // B*N*343
constexpr size_t OFF_NB  = 1280000;                            // > Wk end
constexpr size_t OFF_XE  = OFF_H2T + FHW;
constexpr size_t OFF_LTM = OFF_XE + (size_t)B_ * E_ * HW;
constexpr size_t OFF_PE  = OFF_LTM + (size_t)B_ * HW;
constexpr size_t OFF_YP  = OFF_PE + (size_t)B_ * N_ * D_;
constexpr size_t OFF_LT  = OFF_YP + (size_t)B_ * N_ * D_;
constexpr size_t OFF_SQ  = OFF_LT + (size_t)B_ * N_;
// conv2 prepped weights overlap the xe region (consumed by conv2 before
// conv3 writes xe): 2 buffers x 294912 ushorts = 294,912 floats < 802,816.
constexpr int WPREP_N = 294912;  // 2br * 2kcb * 9idx * 4wv * 64lane * 8j

__device__ __forceinline__ int clampi(int v, int lo, int hi) {
  return min(max(v, lo), hi);
}

typedef __attribute__((ext_vector_type(8))) short short8;
typedef __attribute__((ext_vector_type(4))) float float4v;
} // namespace

// ---------------------------------------------------------------------------
// conv1 (8->64, relu), e+t merged (z: bit0=batch, bit1=branch).
// R9: no launch_bounds min-wave cap (R8's cap caused spills elsewhere); LDS
// store-transpose epilogue: acc -> smem[16][32][17] -> dense float4 stores
// (each wave = 16 pixels x full 64B sectors instead of 64 partial lines).
// Compute order identical to R8 -> bitwise-identical results.
// ---------------------------------------------------------------------------
__global__ __launch_bounds__(256) void conv1m_k(
    const float* __restrict__ x,
    const float* __restrict__ w_e, const float* __restrict__ b_e, float* __restrict__ o_e,
    const float* __restrict__ w_t, const float* __restrict__ b_t, float* __restrict__ o_t) {
  constexpr int CI = 8, COG = 16, CIB = 4;
  constexpr int TR = 18, TC = 34;            // padded tile 18 rows x 34 cols
  constexpr int PLN = TR * TC;               // 612
  constexpr int NST = CIB * PLN;             // 2448
  constexpr int NLD = (NST + 255) / 256;     // 10

  const int cog = blockIdx.x;                // 0..3
  const int tile = blockIdx.y;               // 0..97 (14 x 7)
  const int b = blockIdx.z & 1, br = blockIdx.z >> 1;
  const float* wgt = br ? w_t : w_e;
  const float* bias = br ? b_t : b_e;
  float* out = br ? o_t : o_e;
  const int co0 = cog * COG;
  const int th0 = (tile / 7) * 16, tw0 = (tile % 7) * 32;
  const int tid = threadIdx.x;
  const int tx = tid & 31, ty = tid >> 5;    // ty 0..7, 2 rows each

  // unioned LDS: compute phase uses sW (1536) + sT (2448) = 3984 floats;
  // store phase reuses all of it as a 16x32x17 transpose tile (8704 floats).
  __shared__ float smem[16 * 32 * 17];       // 34816 B
  float* sW = smem;                          // [COG*CI*12]
  float* sT = smem + COG * CI * 12;          // [CIB][PLN]

  for (int s = tid; s < COG * CI * 12; s += 256) {
    int c = s / (CI * 12);
    int rem = s - c * (CI * 12);
    int ci = rem / 12, r = rem - ci * 12;
    sW[s] = (r < 9) ? wgt[((size_t)(co0 + c) * CI + ci) * 9 + r] : 0.f;
  }

  int po[NLD];
  unsigned okm = 0;
#pragma unroll
  for (int j = 0; j < NLD; ++j) {
    int s = tid + 256 * j;
    int pl = s / PLN, rem = s - pl * PLN;
    int lr = rem / TC, lc = rem - lr * TC;
    int gh = th0 + lr - 1, gw = tw0 + lc - 1;
    bool ok = (s < NST) && gh >= 0 && gh < H_ && gw >= 0 && gw < W_;
    po[j] = ok ? (pl * HW + gh * W_ + gw) : 0;
    if (ok) okm |= (1u << j);
  }

  const float* inB = x + (size_t)b * CI * HW;
  float stg[NLD];
#pragma unroll
  for (int j = 0; j < NLD; ++j) {
    float v = inB[po[j]];
    stg[j] = ((okm >> j) & 1) ? v : 0.f;
  }

  float acc[COG][2];
#pragma unroll
  for (int c = 0; c < COG; ++c) {
    float bv = bias[co0 + c];
    acc[c][0] = bv;
    acc[c][1] = bv;
  }

  for (int cb = 0; cb < CI; cb += CIB) {
    __syncthreads();
#pragma unroll
    for (int j = 0; j < NLD; ++j) {
      int s = tid + 256 * j;
      if (s < NST) sT[s] = stg[j];
    }
    __syncthreads();
    if (cb + CIB < CI) {
      const float* inN = inB + (size_t)(cb + CIB) * HW;
#pragma unroll
      for (int j = 0; j < NLD; ++j) {
        float v = inN[po[j]];
        stg[j] = ((okm >> j) & 1) ? v : 0.f;
      }
    }
#pragma unroll
    for (int ci = 0; ci < CIB; ++ci) {
      float iv[4][3];
#pragma unroll
      for (int r = 0; r < 4; ++r)
#pragma unroll
        for (int s2 = 0; s2 < 3; ++s2)
          iv[r][s2] = sT[ci * PLN + (2 * ty + r) * TC + tx + s2];
#pragma unroll
      for (int c = 0; c < COG; ++c) {
        const float4* wp = (const float4*)&sW[(c * CI + cb + ci) * 12];
        float4 wa = wp[0], wb = wp[1], wc = wp[2];
#pragma unroll
        for (int dy = 0; dy < 2; ++dy) {
          acc[c][dy] += iv[dy + 0][0] * wa.x + iv[dy + 0][1] * wa.y +
                        iv[dy + 0][2] * wa.z + iv[dy + 1][0] * wa.w +
                        iv[dy + 1][1] * wb.x + iv[dy + 1][2] * wb.y +
                        iv[dy + 2][0] * wb.z + iv[dy + 2][1] * wb.w +
                        iv[dy + 2][2] * wc.x;
        }
      }
    }
  }

  // ---- store-transpose epilogue ----
  __syncthreads();                            // all waves done reading sW/sT
#pragma unroll
  for (int dy = 0; dy < 2; ++dy) {
    int r = 2 * ty + dy;
#pragma unroll
    for (int c = 0; c < COG; ++c)
      smem[(r * 32 + tx) * 17 + c] = fmaxf(acc[c][dy], 0.f);
  }
  __syncthreads();
  // 2048 float4 chunks (512 pixels x 4 quads); 8 per thread; consecutive
  // lanes cover consecutive (pixel, quad) -> 16 full 64B sectors per wave op.
#pragma unroll
  for (int i = 0; i < 8; ++i) {
    int f = tid + 256 * i;
    int q = f & 3, px = f >> 2;               // px = row*32+col
    int row = px >> 5, col = px & 31;
    float4v v;
#pragma unroll
    for (int e = 0; e < 4; ++e) v[e] = smem[px * 17 + 4 * q + e];
    *(float4v*)&out[(((size_t)b * H_ + th0 + row) * W_ + tw0 + col) * 64 + co0 + 4 * q] = v;
  }
}

// ---------------------------------------------------------------------------
// Weight prep for MFMA conv2 (unchanged).
// ---------------------------------------------------------------------------
__global__ __launch_bounds__(256) void wprep_k(const float* __restrict__ w_e,
                                               const float* __restrict__ w_t,
                                               unsigned short* __restrict__ whi,
                                               unsigned short* __restrict__ wlo) {
  int t = blockIdx.x * 256 + threadIdx.x;
  if (t >= WPREP_N) return;
  int j = t & 7;
  int lane = (t >> 3) & 63;
  int wv = (t >> 9) & 3;
  int t2 = t >> 11;
  int idx = t2 % 9;
  int t3 = t2 / 9;
  int kcb = t3 & 1;
  int br = t3 >> 1;
  const float* wgt = br ? w_t : w_e;
  int co = wv * 16 + (lane & 15);
  int ci = kcb * 32 + 8 * (lane >> 4) + j;
  float v = wgt[((size_t)co * 64 + ci) * 9 + idx];
  unsigned u = __float_as_uint(v);
  unsigned short hi = (unsigned short)(u >> 16);
  float rem = v - __uint_as_float(u & 0xffff0000u);
  unsigned short lo = (unsigned short)(__float_as_uint(rem) >> 16);
  whi[t] = hi;
  wlo[t] = lo;
}

// ---------------------------------------------------------------------------
// conv2 (64->64, relu) via MFMA bf16 3-term hi/lo split (unchanged).
// ---------------------------------------------------------------------------
__global__ __launch_bounds__(256) void conv2_mfma_k(
    const float* __restrict__ in_e, const float* __restrict__ in_t,
    const unsigned short* __restrict__ whi, const unsigned short* __restrict__ wlo,
    const float* __restrict__ b_e, const float* __restrict__ b_t,
    float* __restrict__ out_e, float* __restrict__ out_t) {
  const int tile = blockIdx.x;
  const int b = blockIdx.z & 1;
  const int br = blockIdx.z >> 1;
  const float* in = br ? in_t : in_e;
  const float* bias = br ? b_t : b_e;
  float* out = br ? out_t : out_e;

  const int th0 = (tile / 14) * 16, tw0 = (tile % 14) * 16;
  const int tid = threadIdx.x;
  const int wv = tid >> 6, lane = tid & 63;
  const int q = lane >> 4, n = lane & 15;

  __shared__ unsigned short sT[18 * 18 * 72];
  unsigned* sT32 = (unsigned*)sT;

  float4v acc[16];
#pragma unroll
  for (int pr = 0; pr < 16; ++pr) acc[pr] = (float4v)0.f;

  const float* inB = in + (size_t)b * HW * 64;
  const short8* whi8 = (const short8*)whi;
  const short8* wlo8 = (const short8*)wlo;

  for (int kcb = 0; kcb < 2; ++kcb) {
    __syncthreads();
    for (int jj = 0; jj < 21; ++jj) {
      int s = tid + 256 * jj;
      if (s < 5184) {
        int sp = s >> 4, cp = s & 15;
        int lr = sp / 18, lc = sp - lr * 18;
        int gh = th0 + lr - 1, gw = tw0 + lc - 1;
        float vx = 0.f, vy = 0.f;
        if (gh >= 0 && gh < H_ && gw >= 0 && gw < W_) {
          const float2 vv =
              *(const float2*)&inB[((size_t)gh * W_ + gw) * 64 + kcb * 32 + 2 * cp];
          vx = vv.x; vy = vv.y;
        }
        unsigned u0 = __float_as_uint(vx), u1 = __float_as_uint(vy);
        float r0 = vx - __uint_as_float(u0 & 0xffff0000u);
        float r1 = vy - __uint_as_float(u1 & 0xffff0000u);
        unsigned l0 = __float_as_uint(r0) >> 16, l1 = __float_as_uint(r1) >> 16;
        sT32[sp * 36 + cp] = (u0 >> 16) | ((u1 >> 16) << 16);
        sT32[sp * 36 + 16 + cp] = l0 | (l1 << 16);
      }
    }
    __syncthreads();

    short8 Ah[9], Al[9];
    const int abase = (((br * 2 + kcb) * 9) * 4 + wv) * 64 + lane;
#pragma unroll
    for (int idx = 0; idx < 9; ++idx) {
      Ah[idx] = whi8[abase + idx * 256];
      Al[idx] = wlo8[abase + idx * 256];
    }

#pragma unroll
    for (int r = 0; r < 18; ++r) {
      short8 Bh[3], Bl[3];
#pragma unroll
      for (int kx = 0; kx < 3; ++kx) {
        const unsigned short* p = &sT[(r * 18 + n + kx) * 72 + 8 * q];
        Bh[kx] = *(const short8*)p;
        Bl[kx] = *(const short8*)(p + 32);
      }
#pragma unroll
      for (int ky = 0; ky < 3; ++ky) {
        const int pr = r - ky;
        if (pr >= 0 && pr < 16) {
#pragma unroll
          for (int kx = 0; kx < 3; ++kx) {
            const int idx = ky * 3 + kx;
            acc[pr] = __builtin_amdgcn_mfma_f32_16x16x32_bf16(Ah[idx], Bh[kx], acc[pr], 0, 0, 0);
            acc[pr] = __builtin_amdgcn_mfma_f32_16x16x32_bf16(Al[idx], Bh[kx], acc[pr], 0, 0, 0);
            acc[pr] = __builtin_amdgcn_mfma_f32_16x16x32_bf16(Ah[idx], Bl[kx], acc[pr], 0, 0, 0);
          }
        }
      }
    }
  }

  float4v bv = *(const float4v*)&bias[wv * 16 + 4 * q];
#pragma unroll
  for (int pr = 0; pr < 16; ++pr) {
#pragma unroll
    for (int r = 0; r < 4; ++r) {
      int co = wv * 16 + 4 * q + r;
      float v = fmaxf(acc[pr][r] + bv[r], 0.f);
      out[((size_t)b * 64 + co) * HW + (th0 + pr) * W_ + tw0 + n] = v;
    }
  }
}

// ---------------------------------------------------------------------------
// conv3 e+t merged (64->8 from h2e, 64->1 from h2t, no relu).
// R9: no launch_bounds cap (R8's cap=64 VGPR caused scratch spills -> 227MB
// phantom writes); CIB=8 -> 8 staging rounds. 8x32 tile, grid (196,B).
// Same per-output FMA order -> bitwise-identical results.
// ---------------------------------------------------------------------------
__global__ __launch_bounds__(256) void conv3m_k(
    const float* __restrict__ h2e, const float* __restrict__ h2t,
    const float* __restrict__ w3e, const float* __restrict__ w3t,
    const float* __restrict__ b3e, const float* __restrict__ b3t,
    float* __restrict__ xe, float* __restrict__ ltm) {
  constexpr int CIB = 8;
  constexpr int TR = 10, TC = 34;             // padded tile 10 x 34
  constexpr int PLN = TR * TC;                // 340
  constexpr int NST = 2 * CIB * PLN;          // 5440 (both branches)
  constexpr int NLD = (NST + 255) / 256;      // 22

  const int tile = blockIdx.x;                // 0..195 (28 x 7)
  const int b = blockIdx.y;
  const int th0 = (tile / 7) * 8, tw0 = (tile % 7) * 32;
  const int tid = threadIdx.x;
  const int tx = tid & 31, ty = tid >> 5;     // one output pixel per thread

  __shared__ float sW[9 * 64 * 12];           // 27648 B
  __shared__ float sT[2][CIB][PLN];           // 21760 B

  for (int s = tid; s < 9 * 64 * 12; s += 256) {
    int c = s / (64 * 12);
    int rem = s - c * (64 * 12);
    int ci = rem / 12, r = rem - ci * 12;
    float v = 0.f;
    if (r < 9)
      v = (c < 8) ? w3e[((size_t)c * 64 + ci) * 9 + r]
                  : w3t[(size_t)ci * 9 + r];
    sW[s] = v;
  }

  int po[NLD];
  unsigned okm = 0;
#pragma unroll
  for (int j = 0; j < NLD; ++j) {
    int s = tid + 256 * j;
    int rem2 = s % (CIB * PLN);
    int pl = rem2 / PLN, rem = rem2 % PLN;
    int lr = rem / TC, lc = rem - lr * TC;
    int gh = th0 + lr - 1, gw = tw0 + lc - 1;
    bool ok = (s < NST) && gh >= 0 && gh < H_ && gw >= 0 && gw < W_;
    po[j] = ok ? (pl * HW + gh * W_ + gw) : 0;
    if (ok) okm |= (1u << j);
  }

  const float* heB = h2e + (size_t)b * 64 * HW;
  const float* htB = h2t + (size_t)b * 64 * HW;

  float stg[NLD];
#pragma unroll
  for (int j = 0; j < NLD; ++j) {
    int s = tid + 256 * j;
    const float* src = (s < CIB * PLN) ? heB : htB;
    float v = src[po[j]];
    stg[j] = ((okm >> j) & 1) ? v : 0.f;
  }

  float acc[9];
#pragma unroll
  for (int c = 0; c < 9; ++c) acc[c] = (c < 8) ? b3e[c] : b3t[0];

  for (int cb = 0; cb < 64; cb += CIB) {
    __syncthreads();
#pragma unroll
    for (int j = 0; j < NLD; ++j) {
      int s = tid + 256 * j;
      if (s < NST) ((float*)sT)[s] = stg[j];
    }
    __syncthreads();
    if (cb + CIB < 64) {
      const size_t off = (size_t)(cb + CIB) * HW;
#pragma unroll
      for (int j = 0; j < NLD; ++j) {
        int s = tid + 256 * j;
        const float* src = (s < CIB * PLN) ? (heB + off) : (htB + off);
        float v = src[po[j]];
        stg[j] = ((okm >> j) & 1) ? v : 0.f;
      }
    }
#pragma unroll
    for (int ci = 0; ci < CIB; ++ci) {
      float ive[3][3], ivt[3][3];
#pragma unroll
      for (int r = 0; r < 3; ++r)
#pragma unroll
        for (int s2 = 0; s2 < 3; ++s2) {
          ive[r][s2] = sT[0][ci][(ty + r) * TC + tx + s2];
          ivt[r][s2] = sT[1][ci][(ty + r) * TC + tx + s2];
        }
#pragma unroll
      for (int c = 0; c < 9; ++c) {
        const float4* wp = (const float4*)&sW[(c * 64 + cb + ci) * 12];
        float4 wa = wp[0], wb = wp[1], wc = wp[2];
        const float (*iv)[3] = (c < 8) ? ive : ivt;
        acc[c] += iv[0][0] * wa.x + iv[0][1] * wa.y + iv[0][2] * wa.z +
                  iv[1][0] * wa.w + iv[1][1] * wb.x + iv[1][2] * wb.y +
                  iv[2][0] * wb.z + iv[2][1] * wb.w + iv[2][2] * wc.x;
      }
    }
  }

  const int h = th0 + ty, w = tw0 + tx;
#pragma unroll
  for (int c = 0; c < 8; ++c)
    xe[((size_t)(b * 8 + c) * H_ + h) * W_ + w] = acc[c];
  ltm[(size_t)b * HW + h * W_ + w] = acc[8];
}

// ---------------------------------------------------------------------------
// prep: per (b,n) block (256 thr): write pe row (from xe), yp row (from x),
// reduce sq = ||pe||^2 and lt = mean of 10x10 ltm patch. (unchanged)
// ---------------------------------------------------------------------------
__global__ __launch_bounds__(256) void prep_k(const float* __restrict__ xe,
                                              const float* __restrict__ x,
                                              const float* __restrict__ ltm,
                                              float* __restrict__ pe,
                                              float* __restrict__ yp,
                                              float* __restrict__ lt,
                                              float* __restrict__ sq) {
  const int n = blockIdx.x, b = blockIdx.y;
  const int tid = threadIdx.x;
  const int wv = tid >> 6, lane = tid & 63;
  const int q1 = n / N2, q2 = n % N2;
  const int r0 = q1 * 5, c0 = q2 * 5;

  float s = 0.f;
  float* peR = pe + ((size_t)b * N_ + n) * D_;
  float* ypR = yp + ((size_t)b * N_ + n) * D_;
#pragma unroll
  for (int j = 0; j < 4; ++j) {
    int d = tid + 256 * j;
    if (d < D_) {
      int c = d / 100;
      int rr = (d / 10) % 10;
      int cc = d % 10;
      size_t si = ((size_t)(b * 8 + c) * H_ + r0 + rr) * W_ + c0 + cc;
      float ve = xe[si];
      float vx = x[si];
      peR[d] = ve;
      ypR[d] = vx;
      s += ve * ve;
    }
  }
  float t = 0.f;
  if (tid < 100) t = ltm[(size_t)b * HW + (r0 + tid / 10) * W_ + c0 + tid % 10];

#pragma unroll
  for (int off = 32; off > 0; off >>= 1) {
    s += __shfl_xor(s, off);
    t += __shfl_xor(t, off);
  }
  __shared__ float rs[4], rt[4];
  if (lane == 0) { rs[wv] = s; rt[wv] = t; }
  __syncthreads();
  if (tid == 0) {
    sq[b * N_ + n] = rs[0] + rs[1] + rs[2] + rs[3];
    lt[b * N_ + n] = (rt[0] + rt[1] + rt[2] + rt[3]) * 0.01f;
  }
}

// ---------------------------------------------------------------------------
// attn stage 1 (unchanged).
// ---------------------------------------------------------------------------
__global__ __launch_bounds__(256) void attn_w_k(const float* __restrict__ pe,
                                                const float* __restrict__ lt,
                                                const float* __restrict__ sq,
                                                float* __restrict__ wk) {
  const int wv = threadIdx.x >> 6, lane = threadIdx.x & 63;
  const int n = blockIdx.x * 4 + wv;
  if (n >= N_) return;
  const int b = blockIdx.y;
  const int q1 = n / N2, q2 = n % N2;

  const float* peB = pe + (size_t)b * N_ * D_;
  const float* qrow = peB + (size_t)n * D_;
  float q[13];
#pragma unroll
  for (int t = 0; t < 13; ++t) {
    int s = t * 64 + lane;
    q[t] = (s < D_) ? qrow[s] : 0.f;
  }

  const float sqn = sq[b * N_ + n];
  const float itemp = expf(-lt[b * N_ + n]);
  float gm = -INFINITY;

  for (int o1 = 0; o1 < 7; ++o1) {
    int c1 = clampi(q1 + o1 - 3, 0, N1 - 1);
    const float* rowb = peB + (size_t)(c1 * N2) * D_;
#pragma unroll
    for (int o2 = 0; o2 < 7; ++o2) {
      int c2 = clampi(q2 + o2 - 3, 0, N2 - 1);
      int cn = c1 * N2 + c2;
      const float* crow = rowb + (size_t)c2 * D_;
      float a = 0.f;
#pragma unroll
      for (int t = 0; t < 13; ++t) {
        float v;
        if (t < 12) v = crow[t * 64 + lane];
        else v = (lane < 32) ? crow[768 + lane] : 0.f;
        a += q[t] * v;
      }
#pragma unroll
      for (int off = 32; off > 0; off >>= 1) a += __shfl_xor(a, off);
      float Dv = -(sqn + sq[b * N_ + cn] - 2.f * a);
      float lg = (cn == n) ? -1e9f : Dv * itemp;
      const int m = o1 * 7 + o2;
      gm = (lane == m) ? lg : gm;
    }
  }

  float cur = (lane < M_) ? gm : -INFINITY;
  float* wrow = wk + (size_t)(b * N_ + n) * (M_ * K_);
#pragma unroll
  for (int k = 0; k < K_; ++k) {
    float mx = cur;
#pragma unroll
    for (int off = 32; off > 0; off >>= 1) mx = fmaxf(mx, __shfl_xor(mx, off));
    float e = (lane < M_) ? expf(cur - mx) : 0.f;
    float ssum = e;
#pragma unroll
    for (int off = 32; off > 0; off >>= 1) ssum += __shfl_xor(ssum, off);
    float w = e / ssum;
    if (lane < M_) wrow[lane * K_ + k] = w;
    cur += log1pf(-fminf(w, 1.f - 1e-6f));
  }
}

// ---------------------------------------------------------------------------
// attn stage 2 (unchanged).
// ---------------------------------------------------------------------------
__global__ __launch_bounds__(256) void attn_pv_k(const float* __restrict__ yp,
                                                 const float* __restrict__ wk,
                                                 float* __restrict__ nb) {
  const int wv = threadIdx.x >> 6, lane = threadIdx.x & 63;
  const int n = blockIdx.x;
  const int b = blockIdx.z;
  const int sl = blockIdx.y * 4 + wv;
  const int d = sl * 64 + lane;
  if (d >= D_) return;
  const int q1 = n / N2, q2 = n % N2;

  const float* ypB = yp + (size_t)b * N_ * D_;
  const float* wrow = wk + (size_t)(b * N_ + n) * (M_ * K_);

  float acc[K_];
#pragma unroll
  for (int k = 0; k < K_; ++k) acc[k] = 0.f;

#pragma unroll
  for (int o1 = 0; o1 < 7; ++o1) {
    int c1 = clampi(q1 + o1 - 3, 0, N1 - 1);
#pragma unroll
    for (int o2 = 0; o2 < 7; ++o2) {
      int c2 = clampi(q2 + o2 - 3, 0, N2 - 1);
      int cn = c1 * N2 + c2;
      float y = ypB[(size_t)cn * D_ + d];
      const int m = o1 * 7 + o2;
#pragma unroll
      for (int k = 0; k < K_; ++k) acc[k] += wrow[m * K_ + k] * y;
    }
  }
#pragma unroll
  for (int k = 0; k < K_; ++k)
    nb[(((size_t)k * B_ + b) * N_ + n) * D_ + d] = acc[k];
}

// ---------------------------------------------------------------------------
// Fused output: channels 0..7 copy x; channels 8..63 fold-gather from nb.
// ---------------------------------------------------------------------------
__global__ __launch_bounds__(256) void foldcopy_k(const float* __restrict__ x,
                                                  const float* __restrict__ nb,
                                                  float* __restrict__ out) {
  int i = blockIdx.x * 256 + threadIdx.x;
  constexpr int CT = CIN * (K_ + 1);  // 64
  constexpr int TOT = B_ * CT * HW;
  if (i >= TOT) return;
  int w = i % W_;
  int h = (i / W_) % H_;
  int c64 = (i / HW) % CT;
  int b = i / (HW * CT);
  if (c64 < CIN) {
    out[i] = x[((size_t)b * CIN + c64) * HW + h * W_ + w];
    return;
  }
  int k = (c64 - CIN) >> 3, c = (c64 - CIN) & 7;
  int q1lo = max(0, (h - 5) / 5), q1hi = min(N1 - 1, h / 5);
  int q2lo = max(0, (w - 5) / 5), q2hi = min(N2 - 1, w / 5);
  float val = 0.f;
  int cnt = 0;
  for (int q1 = q1lo; q1 <= q1hi; ++q1)
    for (int q2 = q2lo; q2 <= q2hi; ++q2) {
      int i0 = h - 5 * q1, j0 = w - 5 * q2;
      int nn = q1 * N2 + q2;
      val += nb[(((size_t)k * B_ + b) * N_ + nn) * D_ + c * 100 + i0 * 10 + j0];
      ++cnt;
    }
  out[i] = (cnt > 0) ? val / (float)cnt : 0.f;
}

extern "C" void kernel_launch(void* const* d_in, const int* in_sizes, int n_in,
                              void* d_out, int out_size, void* d_ws,
                              size_t ws_size, hipStream_t stream) {
  const float* x   = (const float*)d_in[0];
  const float* w1e = (const float*)d_in[1];
  const float* b1e = (const float*)d_in[2];
  const float* w2e = (const float*)d_in[3];
  const float* b2e = (const float*)d_in[4];
  const float* w3e = (const float*)d_in[5];
  const float* b3e = (const float*)d_in[6];
  const float* w1t = (const float*)d_in[7];
  const float* b1t = (const float*)d_in[8];
  const float* w2t = (const float*)d_in[9];
  const float* b2t = (const float*)d_in[10];
  const float* w3t = (const float*)d_in[11];
  const float* b3t = (const float*)d_in[12];

  float* ws  = (float*)d_ws;
  float* out = (float*)d_out;

  float* h1e = ws + OFF_H1E;   // channels-last
  float* h1t = ws + OFF_H1T;   // channels-last
  float* h2e = ws + OFF_H2E;   // NCHW
  float* h2t = ws + OFF_H2T;   // NCHW
  float* wkb = ws + OFF_WK;
  float* nb  = ws + OFF_NB;
  float* xe  = ws + OFF_XE;
  float* ltm = ws + OFF_LTM;
  float* pe  = ws + OFF_PE;
  float* yp  = ws + OFF_YP;
  float* lt  = ws + OFF_LT;
  float* sqv = ws + OFF_SQ;
  unsigned short* whi = (unsigned short*)(ws + OFF_XE);  // consumed before xe written
  unsigned short* wlo = whi + WPREP_N;

  // conv2 weight prep
  wprep_k<<<(WPREP_N + 255) / 256, 256, 0, stream>>>(w2e, w2t, whi, wlo);
  // conv1 (8 -> 64, relu), e+t in one dispatch, channels-last output
  conv1m_k<<<dim3(4, 98, 4), 256, 0, stream>>>(x, w1e, b1e, h1e, w1t, b1t, h1t);
  // conv2 (64 -> 64, relu) via MFMA, both branches + batches in one dispatch
  conv2_mfma_k<<<dim3(196, 1, 4), 256, 0, stream>>>(h1e, h1t, whi, wlo, b2e, b2t, h2e, h2t);
  // conv3 (64 -> 8 + 64 -> 1) merged
  conv3m_k<<<dim3(196, B_), 256, 0, stream>>>(h2e, h2t, w3e, w3t, b3e, b3t, xe, ltm);
  // patches + norms + log-temp means fused
  prep_k<<<dim3(N_, B_), 256, 0, stream>>>(xe, x, ltm, pe, yp, lt, sqv);
  // attention stage 1: weights
  attn_w_k<<<dim3((N_ + 3) / 4, B_), 256, 0, stream>>>(pe, lt, sqv, wkb);
  // attention stage 2: weighted neighbor sums
  attn_pv_k<<<dim3(N_, 4, B_), 256, 0, stream>>>(yp, wkb, nb);
  // fused fold + x passthrough
  constexpr int FT = B_ * CIN * (K_ + 1) * HW;
  foldcopy_k<<<(FT + 255) / 256, 256, 0, stream>>>(x, nb, out);
}